// Round 8
// baseline (115.325 us; speedup 1.0000x reference)
//
#include <hip/hip_runtime.h>

// WeightedTensorProduct: out[b, seg[k], c] += x1[b,M1[k],c]*x2[b,M2[k],c]*CG[k]*W[l_ind[k],c]
// Structure is a deterministic function of L=3 -> replicated at compile time.
// R8: packed-fp32 (v_pk_fma_f32) -- 2 adjacent channels per thread as float2.
//     Rationale: R1/R5/R6 structural variants all converge at 23-27us while
//     issue-slot arithmetic says ~5us; the shared property is the ~1500-instr
//     unrolled body (per-wave instruction-stream cost). pk math halves
//     per-entry VALU and cuts code bytes ~40%.
//     cg via s_load (scalar pipe; R5~=R6 showed s_load ~ readlane),
//     w via LDS ds_read_b64, waves_per_eu(2,2) (2 waves/SIMD by construction)
//     -> 256-reg budget, no spill-for-occupancy.

#define LMAX 3
#define MOUT 16          // (L+1)^2
#define CCH 128          // channels
#define NTRI 34
#define NNZ 478
#define NPAIR 156        // nonempty (output-order, triple) pairs

typedef __attribute__((ext_vector_type(2))) float v2f;

struct Tables {
    int n_tri = 0;
    int nnz = 0;
    int np = 0;
    int tl[NTRI] = {}, tl1[NTRI] = {}, tl2[NTRI] = {};
    int M1[NNZ] = {}, M2[NNZ] = {};
    int pair_tri[NPAIR] = {};
    int pair_kstart[NPAIR + 1] = {};
    int mo_pstart[MOUT + 1] = {};
};

constexpr Tables build_tables() {
    Tables T{};
    // triples, insertion order == tri_index order in the reference
    for (int l1 = 0; l1 <= LMAX; ++l1) {
        for (int l2 = 0; l2 <= LMAX; ++l2) {
            int lo = l1 - l2; if (lo < 0) lo = -lo;
            int hi = l1 + l2; if (hi > LMAX) hi = LMAX;
            for (int l = lo; l <= hi; ++l) {
                T.tl[T.n_tri] = l; T.tl1[T.n_tri] = l1; T.tl2[T.n_tri] = l2;
                ++T.n_tri;
            }
        }
    }
    // rows sorted by output order Mo; entries grouped by (Mo, triple)
    for (int l = 0; l <= LMAX; ++l) {
        for (int m = -l; m <= l; ++m) {
            const int Mo = l * l + l + m;
            T.mo_pstart[Mo] = T.np;
            for (int t = 0; t < T.n_tri; ++t) {
                if (T.tl[t] != l) continue;
                const int l1 = T.tl1[t], l2 = T.tl2[t];
                int lo = (-l1 > m - l2) ? -l1 : m - l2;
                int hi = (l1 < m + l2) ? l1 : m + l2;
                if (lo > hi) continue;
                T.pair_tri[T.np] = t;
                T.pair_kstart[T.np] = T.nnz;
                ++T.np;
                for (int m1 = lo; m1 <= hi; ++m1) {
                    const int m2 = m - m1;
                    T.M1[T.nnz] = l1 * l1 + l1 + m1;
                    T.M2[T.nnz] = l2 * l2 + l2 + m2;
                    ++T.nnz;
                }
            }
        }
    }
    T.mo_pstart[MOUT] = T.np;
    T.pair_kstart[T.np] = T.nnz;
    return T;
}

constexpr Tables TB = build_tables();
static_assert(TB.nnz == NNZ, "nnz mismatch vs reference _build_structure");
static_assert(TB.n_tri == NTRI, "n_tri mismatch vs reference _build_structure");
static_assert(TB.np == NPAIR, "pair count mismatch");

__global__ __launch_bounds__(256)
__attribute__((amdgpu_waves_per_eu(2, 2)))
void wtp_kernel(const float* __restrict__ x1, const float* __restrict__ x2,
                const float* __restrict__ w, const float* __restrict__ cg,
                float* __restrict__ out, int B) {
    // per-triple weights staged in LDS: ws[t*CCH + c], 34*128*4 = 17408 B
    __shared__ float ws[NTRI * CCH];
    const int tid = threadIdx.x + 64 * threadIdx.y;     // 0..255
#pragma unroll
    for (int i = 0; i < NTRI * CCH / 256; ++i)          // 17 iters, exact
        ws[i * 256 + tid] = w[i * 256 + tid];
    __syncthreads();

    const int c2 = threadIdx.x;                         // channel-pair 0..63
    const int b = blockIdx.x * blockDim.y + threadIdx.y;
    if (b >= B) return;

    const size_t base = (size_t)b * (MOUT * CCH) + 2 * c2;
    const float* x1b = x1 + base;
    const float* x2b = x2 + base;

    // x1/x2 rows as float2: 8B/lane coalesced (512B per wave-instr)
    v2f x1r[MOUT], x2r[MOUT];
#pragma unroll
    for (int m = 0; m < MOUT; ++m) {
        x1r[m] = *(const v2f*)(x1b + (size_t)m * CCH);
        x2r[m] = *(const v2f*)(x2b + (size_t)m * CCH);
    }

    const float* wsc = ws + 2 * c2;      // ds_read_b64 at offset t*512
    float* outb = out + base;
#pragma unroll
    for (int mo = 0; mo < MOUT; ++mo) {
        v2f acc = {0.f, 0.f};
#pragma unroll
        for (int p = TB.mo_pstart[mo]; p < TB.mo_pstart[mo + 1]; ++p) {
            v2f inner = {0.f, 0.f};
#pragma unroll
            for (int k = TB.pair_kstart[p]; k < TB.pair_kstart[p + 1]; ++k) {
                // cg[k]: wave-uniform, compile-time offset -> s_load (scalar
                // pipe, parallel to VALU)
                const float cgk = cg[k];
                const v2f cg2 = {cgk, cgk};
                inner = __builtin_elementwise_fma(x1r[TB.M1[k]] * x2r[TB.M2[k]],
                                                  cg2, inner);
            }
            const v2f wv = *(const v2f*)(wsc + TB.pair_tri[p] * CCH);
            acc = __builtin_elementwise_fma(wv, inner, acc);
        }
        *(v2f*)(outb + (size_t)mo * CCH) = acc;
    }
}

extern "C" void kernel_launch(void* const* d_in, const int* in_sizes, int n_in,
                              void* d_out, int out_size, void* d_ws, size_t ws_size,
                              hipStream_t stream) {
    const float* x1 = (const float*)d_in[0];
    const float* x2 = (const float*)d_in[1];
    const float* w  = (const float*)d_in[2];
    const float* cg = (const float*)d_in[3];
    float* out = (float*)d_out;

    const int B = in_sizes[0] / (MOUT * CCH);   // 2048

    dim3 block(64, 4, 1);                       // 256 thr: lane-pair = 2 channels
    dim3 grid(B / 4, 1, 1);
    wtp_kernel<<<grid, block, 0, stream>>>(x1, x2, w, cg, out, B);
}

// Round 9
// 98.515 us; speedup vs baseline: 1.1706x; 1.1706x over previous
//
#include <hip/hip_runtime.h>

// WeightedTensorProduct: out[b, seg[k], c] += x1[b,M1[k],c]*x2[b,M2[k],c]*CG[k]*W[l_ind[k],c]
// Structure is a deterministic function of L=3 -> replicated at compile time.
// R6 (base, best measured ~23us kernel): cg via v_readlane from 8 wave-staged
//     VGPRs (no SMEM chain); w via LDS (reg demand ~50 < 64-tier -> no spill);
//     one thread per (b,c), 4 waves/SIMD.
// R9: sched_barrier(0) after the vcg/x1/x2 load block. R8's direct counters
//     (VALUBusy 6%, occupancy 20%, >90% stall) show all variants are
//     latency-stalled, not issue-bound; hypothesis: the scheduler sinks the
//     32 per-thread x-row loads to first use (occupancy heuristic), exposing
//     serial HBM/L2 latency per mo-segment. Pinning forces all loads in
//     flight up-front so their latency overlaps once.

#define LMAX 3
#define MOUT 16          // (L+1)^2
#define CCH 128          // channels
#define NTRI 34
#define NNZ 478
#define NPAIR 156        // nonempty (output-order, triple) pairs
#define NCGV 8           // ceil(NNZ/64) VGPRs holding cg per wave

struct Tables {
    int n_tri = 0;
    int nnz = 0;
    int np = 0;
    int tl[NTRI] = {}, tl1[NTRI] = {}, tl2[NTRI] = {};
    int M1[NNZ] = {}, M2[NNZ] = {};
    int pair_tri[NPAIR] = {};
    int pair_kstart[NPAIR + 1] = {};
    int mo_pstart[MOUT + 1] = {};
};

constexpr Tables build_tables() {
    Tables T{};
    // triples, insertion order == tri_index order in the reference
    for (int l1 = 0; l1 <= LMAX; ++l1) {
        for (int l2 = 0; l2 <= LMAX; ++l2) {
            int lo = l1 - l2; if (lo < 0) lo = -lo;
            int hi = l1 + l2; if (hi > LMAX) hi = LMAX;
            for (int l = lo; l <= hi; ++l) {
                T.tl[T.n_tri] = l; T.tl1[T.n_tri] = l1; T.tl2[T.n_tri] = l2;
                ++T.n_tri;
            }
        }
    }
    // rows sorted by output order Mo; entries grouped by (Mo, triple)
    for (int l = 0; l <= LMAX; ++l) {
        for (int m = -l; m <= l; ++m) {
            const int Mo = l * l + l + m;
            T.mo_pstart[Mo] = T.np;
            for (int t = 0; t < T.n_tri; ++t) {
                if (T.tl[t] != l) continue;
                const int l1 = T.tl1[t], l2 = T.tl2[t];
                int lo = (-l1 > m - l2) ? -l1 : m - l2;
                int hi = (l1 < m + l2) ? l1 : m + l2;
                if (lo > hi) continue;
                T.pair_tri[T.np] = t;
                T.pair_kstart[T.np] = T.nnz;
                ++T.np;
                for (int m1 = lo; m1 <= hi; ++m1) {
                    const int m2 = m - m1;
                    T.M1[T.nnz] = l1 * l1 + l1 + m1;
                    T.M2[T.nnz] = l2 * l2 + l2 + m2;
                    ++T.nnz;
                }
            }
        }
    }
    T.mo_pstart[MOUT] = T.np;
    T.pair_kstart[T.np] = T.nnz;
    return T;
}

constexpr Tables TB = build_tables();
static_assert(TB.nnz == NNZ, "nnz mismatch vs reference _build_structure");
static_assert(TB.n_tri == NTRI, "n_tri mismatch vs reference _build_structure");
static_assert(TB.np == NPAIR, "pair count mismatch");

__global__ __launch_bounds__(256)
void wtp_kernel(const float* __restrict__ x1, const float* __restrict__ x2,
                const float* __restrict__ w, const float* __restrict__ cg,
                float* __restrict__ out, int B) {
    // per-triple weights staged in LDS: ws[t*CCH + c], 34*128*4 = 17408 B
    __shared__ float ws[NTRI * CCH];
    const int tid = threadIdx.x + CCH * threadIdx.y;    // 0..255
#pragma unroll
    for (int i = 0; i < NTRI * CCH / 256; ++i)          // 17 iters, exact
        ws[i * 256 + tid] = w[i * 256 + tid];
    __syncthreads();

    const int c = threadIdx.x;                              // channel 0..127
    const int lane = threadIdx.x & 63;                      // lane within wave
    const int b = blockIdx.x * blockDim.y + threadIdx.y;    // batch
    if (b >= B) return;

    // cg staged across the wave's lanes: vcg[j] lane L holds cg[j*64+L].
    float vcg[NCGV];
#pragma unroll
    for (int j = 0; j < NCGV; ++j) {
        const int idx = j * 64 + lane;
        vcg[j] = (idx < NNZ) ? cg[idx] : 0.f;
    }

    const size_t base = (size_t)b * (MOUT * CCH) + c;
    const float* x1b = x1 + base;
    const float* x2b = x2 + base;

    // x1/x2 rows for this (b,c) into registers: coalesced dword loads per wave
    float x1r[MOUT], x2r[MOUT];
#pragma unroll
    for (int m = 0; m < MOUT; ++m) {
        x1r[m] = x1b[(size_t)m * CCH];
        x2r[m] = x2b[(size_t)m * CCH];
    }

    // Pin the schedule: every global load above must be issued before any
    // compute below (prevents the scheduler sinking loads to first use,
    // which serializes their latency across the 16 mo-segments).
    __builtin_amdgcn_sched_barrier(0);

    const float* wsc = ws + c;   // ds_read_b32, offset t*512, 2-way bank = free
    float* outb = out + base;
#pragma unroll
    for (int mo = 0; mo < MOUT; ++mo) {
        float acc = 0.f;
#pragma unroll
        for (int p = TB.mo_pstart[mo]; p < TB.mo_pstart[mo + 1]; ++p) {
            float inner = 0.f;
#pragma unroll
            for (int k = TB.pair_kstart[p]; k < TB.pair_kstart[p + 1]; ++k) {
                // wave-uniform cg[k]: v_readlane_b32 (VALU, const lane) -> SGPR
                const float cgk = __int_as_float(
                    __builtin_amdgcn_readlane(__float_as_int(vcg[k >> 6]), k & 63));
                inner = fmaf(cgk, x1r[TB.M1[k]] * x2r[TB.M2[k]], inner);
            }
            acc = fmaf(wsc[TB.pair_tri[p] * CCH], inner, acc);
        }
        outb[(size_t)mo * CCH] = acc;
    }
}

extern "C" void kernel_launch(void* const* d_in, const int* in_sizes, int n_in,
                              void* d_out, int out_size, void* d_ws, size_t ws_size,
                              hipStream_t stream) {
    const float* x1 = (const float*)d_in[0];
    const float* x2 = (const float*)d_in[1];
    const float* w  = (const float*)d_in[2];
    const float* cg = (const float*)d_in[3];
    float* out = (float*)d_out;

    const int B = in_sizes[0] / (MOUT * CCH);   // 2048

    dim3 block(CCH, 2, 1);                      // 256 threads: lane = channel
    dim3 grid(B / 2, 1, 1);
    wtp_kernel<<<grid, block, 0, stream>>>(x1, x2, w, cg, out, B);
}